// Round 3
// baseline (23.769 us; speedup 1.0000x reference)
//
#include <hip/hip_runtime.h>
#include <hip/hip_bf16.h>

#define TCTX 500
#define DFEAT 8192
#define BD 16          // full output rows per block (16*2000B = 32000B, 64B-aligned)
#define LDS_S 500      // floats per staged h-row (2000B, 16B-aligned)

__global__ __launch_bounds__(512) void MegaMerge_77283641524594_kernel(
    const float* __restrict__ h,
    const float* __restrict__ c2q,
    const float* __restrict__ q2c,
    float* __restrict__ out)
{
    // h tile staged transposed: hs[d_local * LDS_S + t]
    __shared__ float hs[BD * LDS_S];   // 32000 B

    const int tid = threadIdx.x;
    const int d0  = blockIdx.x * BD;

    // Store-phase mapping: 512 thr = 4 row-groups x 128 t4-lanes.
    const int t4   = tid & 127;         // float4 index along t (0..124 active)
    const int rowg = tid >> 7;          // 0..3; rows rowg, rowg+4, rowg+8, rowg+12
    const bool act = (t4 < 125);        // 125 * 4 = 500 = TCTX

    // ---- Prefetch c2q / q2c into registers (independent of LDS/barrier) ----
    float4 cpre[4], qpre[4];
    if (act) {
        #pragma unroll
        for (int k = 0; k < 4; ++k) {
            const size_t j = (size_t)(d0 + rowg + 4 * k);
            cpre[k] = *reinterpret_cast<const float4*>(&c2q[j * TCTX + t4 * 4]);
            qpre[k] = *reinterpret_cast<const float4*>(&q2c[j * TCTX + t4 * 4]);
        }
    }

    // ---- Stage h[t, d0:d0+16] transposed into LDS ----
    // 4 lanes x float4 = one full 64B line per h-row; 128 rows per pass.
    {
        const int dc = (tid & 3) * 4;   // 0,4,8,12
        const int tr = tid >> 2;        // 0..127
        #pragma unroll
        for (int p = 0; p < 4; ++p) {
            const int t = p * 128 + tr;
            if (t < TCTX) {
                const float4 v = *reinterpret_cast<const float4*>(
                    &h[(size_t)t * DFEAT + d0 + dc]);
                hs[(dc + 0) * LDS_S + t] = v.x;   // 2-way bank aliasing max (free)
                hs[(dc + 1) * LDS_S + t] = v.y;
                hs[(dc + 2) * LDS_S + t] = v.z;
                hs[(dc + 3) * LDS_S + t] = v.w;
            }
        }
    }
    __syncthreads();

    // ---- Store phase: full-row, full-line writes; data already in regs/LDS ----
    if (act) {
        const size_t sec = (size_t)DFEAT * TCTX;
        #pragma unroll
        for (int k = 0; k < 4; ++k) {
            const int dl = rowg + 4 * k;
            const size_t j = (size_t)(d0 + dl);
            const float4 hv = *reinterpret_cast<const float4*>(
                &hs[dl * LDS_S + t4 * 4]);      // linear 16B/lane: conflict-free
            const float4 c = cpre[k];
            const float4 q = qpre[k];
            const float4 hc = make_float4(hv.x * c.x, hv.y * c.y,
                                          hv.z * c.z, hv.w * c.w);
            const float4 hq = make_float4(hv.x * q.x, hv.y * q.y,
                                          hv.z * q.z, hv.w * q.w);
            const size_t o = j * TCTX + t4 * 4;
            *reinterpret_cast<float4*>(&out[o          ]) = hv;  // H^T
            *reinterpret_cast<float4*>(&out[o + sec    ]) = c;   // c2q copy
            *reinterpret_cast<float4*>(&out[o + 2 * sec]) = hc;  // H*C
            *reinterpret_cast<float4*>(&out[o + 3 * sec]) = hq;  // H*Q
        }
    }
}

extern "C" void kernel_launch(void* const* d_in, const int* in_sizes, int n_in,
                              void* d_out, int out_size, void* d_ws, size_t ws_size,
                              hipStream_t stream) {
    const float* h   = (const float*)d_in[0];
    const float* c2q = (const float*)d_in[1];
    const float* q2c = (const float*)d_in[2];
    float* out = (float*)d_out;

    dim3 grid(DFEAT / BD);   // 512 blocks, each owns 16 complete output rows
    dim3 block(512);
    MegaMerge_77283641524594_kernel<<<grid, block, 0, stream>>>(h, c2q, q2c, out);
}